// Round 6
// baseline (150.144 us; speedup 1.0000x reference)
//
#include <hip/hip_runtime.h>
#include <math.h>

// Problem dims (fixed by reference)
#define BD   4
#define TD   8
#define CD   32
#define WD   40
#define KD   9       // final top-k
#define HWD  1600
#define TM1  7       // T-1
#define NPAIR (BD * TM1)
#define OUTK ((size_t)NPAIR * HWD * KD)   // 403200
#define CL   6       // per-class sorted-column length (4 columns per lane)
#define NEX  12      // candidates re-ranked per lane

// d_ws layout (bytes)
#define FNW_OFF   0                        // bf16 normalized, [bt][node][16 uints] = 3.2768 MB
#define TRAW_OFF  3276800                  // raw f32 node-major, [bt][node][32]   = 6.5536 MB
#define RND_OFF   9830400                  // f64 inv-norms, [bt][node]            = 0.4096 MB

typedef __attribute__((ext_vector_type(8))) short short8;   // 8 bf16 (4 VGPRs)
typedef __attribute__((ext_vector_type(4))) float f32x4;

__device__ __forceinline__ uint f2bf(float f) {             // f32 -> bf16 bits (RNE)
    uint u = __float_as_uint(f);
    return (u + 0x7FFFu + ((u >> 16) & 1u)) >> 16;
}

// ------- kernel 1: per-node normalize (bf16), raw transpose (f32), f64 norms -------
// 4 threads per (bt, node): thread q handles channels [8q, 8q+8)  (UNCHANGED from R4/R5)
__global__ __launch_bounds__(256)
void prep_kernel(const float* __restrict__ x, uint* __restrict__ fnw,
                 float* __restrict__ traw, double* __restrict__ rnd)
{
    const int gid  = blockIdx.x * 256 + threadIdx.x;   // 0 .. 204799
    const int q    = gid & 3;
    const int idx  = gid >> 2;                          // 0 .. 51199
    const int bt   = idx / HWD;
    const int node = idx - bt * HWD;

    const float* src = x + (size_t)bt * CD * HWD + node;
    float v[8];
    float ssq = 0.f;
    double ssd = 0.0;
#pragma unroll
    for (int cc = 0; cc < 8; ++cc) {
        const float a = src[(size_t)(q * 8 + cc) * HWD];
        v[cc] = a;
        ssq += a * a;
        ssd = fma((double)a, (double)a, ssd);
    }
    // 4-lane reduce (lanes 4k..4k+3 share a node)
    ssq += __shfl_xor(ssq, 1);  ssq += __shfl_xor(ssq, 2);
    ssd += __shfl_xor(ssd, 1);  ssd += __shfl_xor(ssd, 2);

    const float rn = 1.0f / sqrtf(ssq + 1e-8f);
    if (q == 0) rnd[(size_t)bt * HWD + node] = 1.0 / sqrt(ssd + 1e-8);

    uint* dstb = fnw + (size_t)(bt * HWD + node) * 16 + q * 4;
    const uint w0 = f2bf(v[0]*rn) | (f2bf(v[1]*rn) << 16);
    const uint w1 = f2bf(v[2]*rn) | (f2bf(v[3]*rn) << 16);
    const uint w2 = f2bf(v[4]*rn) | (f2bf(v[5]*rn) << 16);
    const uint w3 = f2bf(v[6]*rn) | (f2bf(v[7]*rn) << 16);
    *(uint4*)dstb = make_uint4(w0, w1, w2, w3);

    float* dstr = traw + (size_t)(bt * HWD + node) * 32 + q * 8;
    ((float4*)dstr)[0] = make_float4(v[0], v[1], v[2], v[3]);
    ((float4*)dstr)[1] = make_float4(v[4], v[5], v[6], v[7]);
}

// ------- kernel 2: MFMA phase-1 (j-split across wave pairs) + f64 re-rank -------
// Block = 256 thr = 4 waves: iq = wid&1 (16-row i-sub-block), half = wid>>1 (j-half).
// Each wave scans 50 tiles (800 j's); per-lane per-class sorted columns as R5.
// Half-1 extracts sorted top-12 packed -> LDS; half-0 merges (exact same candidate
// set as a full scan) and runs the validated f64 re-rank / tournament / output.
__global__ __launch_bounds__(256, 4)
void topk_kernel(const uint* __restrict__ fnw, const float* __restrict__ traw,
                 const double* __restrict__ rnd, float* __restrict__ out)
{
    __shared__ uint s_ext[2][64][NEX];    // 6 KB: half-1 sorted candidates

    const int tid  = threadIdx.x;
    const int lane = tid & 63;
    const int wid  = tid >> 6;
    const int li   = lane & 15;
    const int gr   = lane >> 4;          // 0..3
    const int iq   = wid & 1;            // i sub-block within the 32 i's
    const int half = wid >> 1;           // j-half 0/1

    // bijective XCD swizzle of 1400 blocks (1400 % 8 == 0)
    const int bid  = blockIdx.x;
    const int xcd  = bid & 7;
    const int kk   = bid >> 3;            // 0..174
    const int work = xcd * 175 + kk;
    const int f    = work / 50;           // frame pair 0..27
    const int rem  = work - f * 50;       // i-block32 0..49
    const int b    = f / TM1;
    const int t    = f - b * TM1;
    const int bt0  = b * TD + t;
    const int bt1  = bt0 + 1;
    const int i    = rem * 32 + iq * 16 + li;

    const uint* fA = fnw + (size_t)bt0 * HWD * 16;   // frame t   (B operand)
    const uint* fB = fnw + (size_t)bt1 * HWD * 16;   // frame t+1 (A operand)

    // B-operand fragment: my i-node, constant across the whole j-scan
    const short8 bF = *(const short8*)(fA + (size_t)i * 16 + gr * 4);

    // 4 sorted-descending columns of CL packed u32; 0 = empty sentinel
    uint C[4][CL];
#pragma unroll
    for (int r = 0; r < 4; ++r)
#pragma unroll
        for (int k = 0; k < CL; ++k) C[r][k] = 0u;

    // per-slot inverted-index registers: jr[r] = 2047 - (j of slot r)
    int jr[4];
#pragma unroll
    for (int r = 0; r < 4; ++r) jr[r] = 2047 - half * 800 - 4 * gr - r;

    const f32x4 one4 = {1.f, 1.f, 1.f, 1.f};   // C=1: acc = 1 + sim >= 0 -> uint-monotonic

#define LDT(dst, s) dst = *(const short8*)(fB + (size_t)((s) * 16 + li) * 16 + gr * 4)

#define INSTILE(acc) do {                                              \
    _Pragma("unroll")                                                  \
    for (int r = 0; r < 4; ++r) {                                      \
        int ub = __float_as_int((acc)[r]);                             \
        ub = ub < 0 ? 0 : ub;                                          \
        uint u = ((uint)ub & 0xFFFFF800u) | (uint)jr[r];               \
        uint tv = u;                                                   \
        _Pragma("unroll")                                              \
        for (int k = 0; k < CL; ++k) {                                 \
            const uint lo = min(C[r][k], tv);                          \
            C[r][k] = max(C[r][k], tv);                                \
            tv = lo;                                                   \
        }                                                              \
        jr[r] -= 16;                                                   \
    }                                                                  \
} while (0)

    const int s0 = half * 50;
    short8 a0, a1, a2, a3;
    LDT(a0, s0); LDT(a1, s0 + 1); LDT(a2, s0 + 2); LDT(a3, s0 + 3);

    // main loop: 11 iterations, tiles s0..s0+43; loads run 4 tiles ahead
    for (int sb = s0; sb < s0 + 44; sb += 4) {
        f32x4 acc;
        acc = __builtin_amdgcn_mfma_f32_16x16x32_bf16(a0, bF, one4, 0, 0, 0);
        LDT(a0, sb + 4);
        INSTILE(acc);
        acc = __builtin_amdgcn_mfma_f32_16x16x32_bf16(a1, bF, one4, 0, 0, 0);
        LDT(a1, sb + 5);
        INSTILE(acc);
        acc = __builtin_amdgcn_mfma_f32_16x16x32_bf16(a2, bF, one4, 0, 0, 0);
        LDT(a2, sb + 6);
        INSTILE(acc);
        acc = __builtin_amdgcn_mfma_f32_16x16x32_bf16(a3, bF, one4, 0, 0, 0);
        LDT(a3, sb + 7);
        INSTILE(acc);
    }
    // tail: tiles s0+44..49
    {
        f32x4 acc;
        acc = __builtin_amdgcn_mfma_f32_16x16x32_bf16(a0, bF, one4, 0, 0, 0);
        LDT(a0, s0 + 48);
        INSTILE(acc);
        acc = __builtin_amdgcn_mfma_f32_16x16x32_bf16(a1, bF, one4, 0, 0, 0);
        LDT(a1, s0 + 49);
        INSTILE(acc);
        acc = __builtin_amdgcn_mfma_f32_16x16x32_bf16(a2, bF, one4, 0, 0, 0);
        INSTILE(acc);
        acc = __builtin_amdgcn_mfma_f32_16x16x32_bf16(a3, bF, one4, 0, 0, 0);
        INSTILE(acc);
        acc = __builtin_amdgcn_mfma_f32_16x16x32_bf16(a0, bF, one4, 0, 0, 0);
        INSTILE(acc);
        acc = __builtin_amdgcn_mfma_f32_16x16x32_bf16(a1, bF, one4, 0, 0, 0);
        INSTILE(acc);
    }
#undef LDT
#undef INSTILE

    // ---- extract this half's top-NEX in descending packed order (branchless pops) ----
    uint sA[NEX];
#pragma unroll
    for (int rd = 0; rd < NEX; ++rd) {
        const uint m = max(max(C[0][0], C[1][0]), max(C[2][0], C[3][0]));
#pragma unroll
        for (int r = 0; r < 4; ++r) {
            const bool e = (C[r][0] == m);
#pragma unroll
            for (int k = 0; k < CL - 1; ++k) C[r][k] = e ? C[r][k + 1] : C[r][k];
            C[r][CL - 1] = e ? 0u : C[r][CL - 1];
        }
        sA[rd] = m;
    }

    if (half == 1) {
#pragma unroll
        for (int k = 0; k < NEX; ++k) s_ext[iq][lane][k] = sA[k];
    }
    __syncthreads();
    if (half == 1) return;

    // ---- half-0: load partner's sorted list, 2-list merge-pop + f64 re-rank ----
    uint sB[NEX];
#pragma unroll
    for (int q = 0; q < 3; ++q) {
        const uint4 v4 = *(const uint4*)&s_ext[iq][lane][q * 4];
        sB[q*4+0] = v4.x; sB[q*4+1] = v4.y; sB[q*4+2] = v4.z; sB[q*4+3] = v4.w;
    }

    const float* tA = traw + (size_t)bt0 * HWD * 32 + (size_t)i * 32;
    float arf[CD];
#pragma unroll
    for (int q = 0; q < 8; ++q) {
        const float4 r4 = ((const float4*)tA)[q];
        arf[4*q+0] = r4.x; arf[4*q+1] = r4.y; arf[4*q+2] = r4.z; arf[4*q+3] = r4.w;
    }
    const double rna = rnd[(size_t)bt0 * HWD + i];
    const float*  trB = traw + (size_t)bt1 * HWD * 32;
    const double* rnB = rnd + (size_t)bt1 * HWD;

    double fv[KD]; int fi[KD];
#pragma unroll
    for (int k = 0; k < KD; ++k) { fv[k] = -1.0e300; fi[k] = 0; }

    for (int rd = 0; rd < NEX; ++rd) {
        // pop global max of the two sorted lists (packed values unique)
        const bool tAh = sA[0] > sB[0];
        const uint m = tAh ? sA[0] : sB[0];
#pragma unroll
        for (int k = 0; k < NEX - 1; ++k) {
            sA[k] = tAh ? sA[k + 1] : sA[k];
            sB[k] = tAh ? sB[k] : sB[k + 1];
        }
        const int j = 2047 - (int)(m & 2047u);
        const float4* rb = (const float4*)(trB + (size_t)j * 32);
        double d0 = 0.0, d1 = 0.0, d2 = 0.0, d3 = 0.0;
#pragma unroll
        for (int q = 0; q < 8; ++q) {
            const float4 r4 = rb[q];
            d0 = fma((double)arf[4*q+0], (double)r4.x, d0);
            d1 = fma((double)arf[4*q+1], (double)r4.y, d1);
            d2 = fma((double)arf[4*q+2], (double)r4.z, d2);
            d3 = fma((double)arf[4*q+3], (double)r4.w, d3);
        }
        const double val = ((d0 + d1) + (d2 + d3)) * rna * rnB[j];
        if (val > fv[KD - 1]) {          // desc packed order => stable tie order
            bool bg[KD];
#pragma unroll
            for (int k = 0; k < KD; ++k) bg[k] = val > fv[k];
#pragma unroll
            for (int k = KD - 1; k >= 1; --k) {
                fv[k] = bg[k - 1] ? fv[k - 1] : (bg[k] ? val : fv[k]);
                fi[k] = bg[k - 1] ? fi[k - 1] : (bg[k] ? j : fi[k]);
            }
            if (bg[0]) { fv[0] = val; fi[0] = j; }
        }
    }

    // ---- 4-way sorted-list tournament merge across the i-group (lanes l^16, l^32) ----
    // j-coverage disjoint across group lanes => winner pops exactly one head
    double w9v[KD]; int w9j[KD];
#pragma unroll
    for (int rd = 0; rd < KD; ++rd) {
        double hv = fv[0]; int hj = fi[0];
        {
            const double ov = __shfl_xor(hv, 16); const int oj = __shfl_xor(hj, 16);
            const bool tk = (ov > hv) || (ov == hv && oj < hj);
            hv = tk ? ov : hv; hj = tk ? oj : hj;
        }
        {
            const double ov = __shfl_xor(hv, 32); const int oj = __shfl_xor(hj, 32);
            const bool tk = (ov > hv) || (ov == hv && oj < hj);
            hv = tk ? ov : hv; hj = tk ? oj : hj;
        }
        w9v[rd] = hv; w9j[rd] = hj;
        const bool win = (fi[0] == hj);   // head sentinels impossible within 9 rounds
#pragma unroll
        for (int k = 0; k < KD - 1; ++k) {
            fv[k] = win ? fv[k + 1] : fv[k];
            fi[k] = win ? fi[k + 1] : fi[k];
        }
        if (win) fv[KD - 1] = -1.0e300;
    }

    // ---- outputs: all 4 group lanes hold identical winners; split the stores ----
    double wsum = 0.0;
#pragma unroll
    for (int k = 0; k < KD; ++k) wsum += w9v[k];
    const double winv = 1.0 / (wsum + 1e-8);

    const size_t base = ((size_t)f * HWD + i) * KD;
    const int sy = i / WD, sx = i - sy * WD;
    if (gr == 0) {
#pragma unroll
        for (int k = 0; k < KD; ++k) out[base + k] = (float)(w9v[k] * winv);
    } else if (gr == 1) {
#pragma unroll
        for (int k = 0; k < KD; ++k) out[OUTK + base + k] = (float)w9j[k];
    } else if (gr == 2) {
#pragma unroll
        for (int k = 0; k < KD; ++k) {
            const int j = w9j[k];
            out[2 * OUTK + (base + k) * 2 + 0] = (float)(j / WD - sy);
        }
    } else {
#pragma unroll
        for (int k = 0; k < KD; ++k) {
            const int j = w9j[k];
            out[2 * OUTK + (base + k) * 2 + 1] = (float)(j - (j / WD) * WD - sx);
        }
    }
}

extern "C" void kernel_launch(void* const* d_in, const int* in_sizes, int n_in,
                              void* d_out, int out_size, void* d_ws, size_t ws_size,
                              hipStream_t stream)
{
    const float* x = (const float*)d_in[0];
    uint*   fnw  = (uint*)((char*)d_ws + FNW_OFF);
    float*  traw = (float*)((char*)d_ws + TRAW_OFF);
    double* rnd  = (double*)((char*)d_ws + RND_OFF);
    float*  out  = (float*)d_out;

    prep_kernel<<<dim3((TD * BD * HWD * 4) / 256), 256, 0, stream>>>(x, fnw, traw, rnd);
    topk_kernel<<<dim3(NPAIR * 50), 256, 0, stream>>>(fnw, traw, rnd, out);
}

// Round 7
// 134.983 us; speedup vs baseline: 1.1123x; 1.1123x over previous
//
#include <hip/hip_runtime.h>
#include <math.h>

// Problem dims (fixed by reference)
#define BD   4
#define TD   8
#define CD   32
#define WD   40
#define KD   9       // final top-k
#define HWD  1600
#define TM1  7       // T-1
#define NPAIR (BD * TM1)
#define OUTK ((size_t)NPAIR * HWD * KD)   // 403200
#define CL   6       // per-class sorted-column length (4 columns per lane)
#define NEX  12      // candidates re-ranked per lane

// d_ws layout (bytes)
#define FNW_OFF   0                        // bf16 normalized, [bt][node][16 uints] = 3.2768 MB
#define TRAW_OFF  3276800                  // raw f32 node-major, [bt][node][32]   = 6.5536 MB
#define RND_OFF   9830400                  // f64 inv-norms, [bt][node]            = 0.4096 MB

typedef __attribute__((ext_vector_type(8))) short short8;   // 8 bf16 (4 VGPRs)
typedef __attribute__((ext_vector_type(4))) float f32x4;

__device__ __forceinline__ uint f2bf(float f) {             // f32 -> bf16 bits (RNE)
    uint u = __float_as_uint(f);
    return (u + 0x7FFFu + ((u >> 16) & 1u)) >> 16;
}

// ------- kernel 1: per-node normalize (bf16), raw transpose (f32), f64 norms -------
// 4 threads per (bt, node): thread q handles channels [8q, 8q+8)  (UNCHANGED)
__global__ __launch_bounds__(256)
void prep_kernel(const float* __restrict__ x, uint* __restrict__ fnw,
                 float* __restrict__ traw, double* __restrict__ rnd)
{
    const int gid  = blockIdx.x * 256 + threadIdx.x;   // 0 .. 204799
    const int q    = gid & 3;
    const int idx  = gid >> 2;                          // 0 .. 51199
    const int bt   = idx / HWD;
    const int node = idx - bt * HWD;

    const float* src = x + (size_t)bt * CD * HWD + node;
    float v[8];
    float ssq = 0.f;
    double ssd = 0.0;
#pragma unroll
    for (int cc = 0; cc < 8; ++cc) {
        const float a = src[(size_t)(q * 8 + cc) * HWD];
        v[cc] = a;
        ssq += a * a;
        ssd = fma((double)a, (double)a, ssd);
    }
    // 4-lane reduce (lanes 4k..4k+3 share a node)
    ssq += __shfl_xor(ssq, 1);  ssq += __shfl_xor(ssq, 2);
    ssd += __shfl_xor(ssd, 1);  ssd += __shfl_xor(ssd, 2);

    const float rn = 1.0f / sqrtf(ssq + 1e-8f);
    if (q == 0) rnd[(size_t)bt * HWD + node] = 1.0 / sqrt(ssd + 1e-8);

    uint* dstb = fnw + (size_t)(bt * HWD + node) * 16 + q * 4;
    const uint w0 = f2bf(v[0]*rn) | (f2bf(v[1]*rn) << 16);
    const uint w1 = f2bf(v[2]*rn) | (f2bf(v[3]*rn) << 16);
    const uint w2 = f2bf(v[4]*rn) | (f2bf(v[5]*rn) << 16);
    const uint w3 = f2bf(v[6]*rn) | (f2bf(v[7]*rn) << 16);
    *(uint4*)dstb = make_uint4(w0, w1, w2, w3);

    float* dstr = traw + (size_t)(bt * HWD + node) * 32 + q * 8;
    ((float4*)dstr)[0] = make_float4(v[0], v[1], v[2], v[3]);
    ((float4*)dstr)[1] = make_float4(v[4], v[5], v[6], v[7]);
}

// ------- kernel 2: MFMA phase-1 (j-split across wave pairs) + f64 re-rank -------
// Block = 256 thr = 4 waves: iq = wid&1 (16-row i-sub-block), half = wid>>1 (j-half).
// Each wave scans 50 tiles (800 j's); per-lane per-class sorted columns.
// Half-1 extracts sorted top-12 packed -> LDS; half-0 merges (exact same candidate
// set as a full scan) and runs the validated f64 re-rank / tournament / output.
// R7: launch_bounds reverted to (256) — R6's (256,4) forced VGPR<=64 and spilled
// the candidate arrays to scratch (WRITE_SIZE 6.3->28 MB). 76 VGPR, no spill.
__global__ __launch_bounds__(256)
void topk_kernel(const uint* __restrict__ fnw, const float* __restrict__ traw,
                 const double* __restrict__ rnd, float* __restrict__ out)
{
    __shared__ uint s_ext[2][64][NEX];    // 6 KB: half-1 sorted candidates

    const int tid  = threadIdx.x;
    const int lane = tid & 63;
    const int wid  = tid >> 6;
    const int li   = lane & 15;
    const int gr   = lane >> 4;          // 0..3
    const int iq   = wid & 1;            // i sub-block within the 32 i's
    const int half = wid >> 1;           // j-half 0/1

    // bijective XCD swizzle of 1400 blocks (1400 % 8 == 0)
    const int bid  = blockIdx.x;
    const int xcd  = bid & 7;
    const int kk   = bid >> 3;            // 0..174
    const int work = xcd * 175 + kk;
    const int f    = work / 50;           // frame pair 0..27
    const int rem  = work - f * 50;       // i-block32 0..49
    const int b    = f / TM1;
    const int t    = f - b * TM1;
    const int bt0  = b * TD + t;
    const int bt1  = bt0 + 1;
    const int i    = rem * 32 + iq * 16 + li;

    const uint* fA = fnw + (size_t)bt0 * HWD * 16;   // frame t   (B operand)
    const uint* fB = fnw + (size_t)bt1 * HWD * 16;   // frame t+1 (A operand)

    // B-operand fragment: my i-node, constant across the whole j-scan
    const short8 bF = *(const short8*)(fA + (size_t)i * 16 + gr * 4);

    // 4 sorted-descending columns of CL packed u32; 0 = empty sentinel
    uint C[4][CL];
#pragma unroll
    for (int r = 0; r < 4; ++r)
#pragma unroll
        for (int k = 0; k < CL; ++k) C[r][k] = 0u;

    // per-slot inverted-index registers: jr[r] = 2047 - (j of slot r)
    int jr[4];
#pragma unroll
    for (int r = 0; r < 4; ++r) jr[r] = 2047 - half * 800 - 4 * gr - r;

    const f32x4 one4 = {1.f, 1.f, 1.f, 1.f};   // C=1: acc = 1 + sim >= 0 -> uint-monotonic

#define LDT(dst, s) dst = *(const short8*)(fB + (size_t)((s) * 16 + li) * 16 + gr * 4)

#define INSTILE(acc) do {                                              \
    _Pragma("unroll")                                                  \
    for (int r = 0; r < 4; ++r) {                                      \
        int ub = __float_as_int((acc)[r]);                             \
        ub = ub < 0 ? 0 : ub;                                          \
        uint u = ((uint)ub & 0xFFFFF800u) | (uint)jr[r];               \
        uint tv = u;                                                   \
        _Pragma("unroll")                                              \
        for (int k = 0; k < CL; ++k) {                                 \
            const uint lo = min(C[r][k], tv);                          \
            C[r][k] = max(C[r][k], tv);                                \
            tv = lo;                                                   \
        }                                                              \
        jr[r] -= 16;                                                   \
    }                                                                  \
} while (0)

    const int s0 = half * 50;
    short8 a0, a1, a2, a3;
    LDT(a0, s0); LDT(a1, s0 + 1); LDT(a2, s0 + 2); LDT(a3, s0 + 3);

    // main loop: 11 iterations, tiles s0..s0+43; loads run 4 tiles ahead
    for (int sb = s0; sb < s0 + 44; sb += 4) {
        f32x4 acc;
        acc = __builtin_amdgcn_mfma_f32_16x16x32_bf16(a0, bF, one4, 0, 0, 0);
        LDT(a0, sb + 4);
        INSTILE(acc);
        acc = __builtin_amdgcn_mfma_f32_16x16x32_bf16(a1, bF, one4, 0, 0, 0);
        LDT(a1, sb + 5);
        INSTILE(acc);
        acc = __builtin_amdgcn_mfma_f32_16x16x32_bf16(a2, bF, one4, 0, 0, 0);
        LDT(a2, sb + 6);
        INSTILE(acc);
        acc = __builtin_amdgcn_mfma_f32_16x16x32_bf16(a3, bF, one4, 0, 0, 0);
        LDT(a3, sb + 7);
        INSTILE(acc);
    }
    // tail: tiles s0+44..49
    {
        f32x4 acc;
        acc = __builtin_amdgcn_mfma_f32_16x16x32_bf16(a0, bF, one4, 0, 0, 0);
        LDT(a0, s0 + 48);
        INSTILE(acc);
        acc = __builtin_amdgcn_mfma_f32_16x16x32_bf16(a1, bF, one4, 0, 0, 0);
        LDT(a1, s0 + 49);
        INSTILE(acc);
        acc = __builtin_amdgcn_mfma_f32_16x16x32_bf16(a2, bF, one4, 0, 0, 0);
        INSTILE(acc);
        acc = __builtin_amdgcn_mfma_f32_16x16x32_bf16(a3, bF, one4, 0, 0, 0);
        INSTILE(acc);
        acc = __builtin_amdgcn_mfma_f32_16x16x32_bf16(a0, bF, one4, 0, 0, 0);
        INSTILE(acc);
        acc = __builtin_amdgcn_mfma_f32_16x16x32_bf16(a1, bF, one4, 0, 0, 0);
        INSTILE(acc);
    }
#undef LDT
#undef INSTILE

    // ---- extract this half's top-NEX in descending packed order (branchless pops) ----
    uint sA[NEX];
#pragma unroll
    for (int rd = 0; rd < NEX; ++rd) {
        const uint m = max(max(C[0][0], C[1][0]), max(C[2][0], C[3][0]));
#pragma unroll
        for (int r = 0; r < 4; ++r) {
            const bool e = (C[r][0] == m);
#pragma unroll
            for (int k = 0; k < CL - 1; ++k) C[r][k] = e ? C[r][k + 1] : C[r][k];
            C[r][CL - 1] = e ? 0u : C[r][CL - 1];
        }
        sA[rd] = m;
    }

    if (half == 1) {
#pragma unroll
        for (int k = 0; k < NEX; ++k) s_ext[iq][lane][k] = sA[k];
    }
    __syncthreads();
    if (half == 1) return;

    // ---- half-0: load partner's sorted list, 2-list merge-pop + f64 re-rank ----
    uint sB[NEX];
#pragma unroll
    for (int q = 0; q < 3; ++q) {
        const uint4 v4 = *(const uint4*)&s_ext[iq][lane][q * 4];
        sB[q*4+0] = v4.x; sB[q*4+1] = v4.y; sB[q*4+2] = v4.z; sB[q*4+3] = v4.w;
    }

    const float* tA = traw + (size_t)bt0 * HWD * 32 + (size_t)i * 32;
    float arf[CD];
#pragma unroll
    for (int q = 0; q < 8; ++q) {
        const float4 r4 = ((const float4*)tA)[q];
        arf[4*q+0] = r4.x; arf[4*q+1] = r4.y; arf[4*q+2] = r4.z; arf[4*q+3] = r4.w;
    }
    const double rna = rnd[(size_t)bt0 * HWD + i];
    const float*  trB = traw + (size_t)bt1 * HWD * 32;
    const double* rnB = rnd + (size_t)bt1 * HWD;

    double fv[KD]; int fi[KD];
#pragma unroll
    for (int k = 0; k < KD; ++k) { fv[k] = -1.0e300; fi[k] = 0; }

    for (int rd = 0; rd < NEX; ++rd) {
        // pop global max of the two sorted lists (packed values unique)
        const bool tAh = sA[0] > sB[0];
        const uint m = tAh ? sA[0] : sB[0];
#pragma unroll
        for (int k = 0; k < NEX - 1; ++k) {
            sA[k] = tAh ? sA[k + 1] : sA[k];
            sB[k] = tAh ? sB[k] : sB[k + 1];
        }
        const int j = 2047 - (int)(m & 2047u);
        const float4* rb = (const float4*)(trB + (size_t)j * 32);
        double d0 = 0.0, d1 = 0.0, d2 = 0.0, d3 = 0.0;
#pragma unroll
        for (int q = 0; q < 8; ++q) {
            const float4 r4 = rb[q];
            d0 = fma((double)arf[4*q+0], (double)r4.x, d0);
            d1 = fma((double)arf[4*q+1], (double)r4.y, d1);
            d2 = fma((double)arf[4*q+2], (double)r4.z, d2);
            d3 = fma((double)arf[4*q+3], (double)r4.w, d3);
        }
        const double val = ((d0 + d1) + (d2 + d3)) * rna * rnB[j];
        if (val > fv[KD - 1]) {          // desc packed order => stable tie order
            bool bg[KD];
#pragma unroll
            for (int k = 0; k < KD; ++k) bg[k] = val > fv[k];
#pragma unroll
            for (int k = KD - 1; k >= 1; --k) {
                fv[k] = bg[k - 1] ? fv[k - 1] : (bg[k] ? val : fv[k]);
                fi[k] = bg[k - 1] ? fi[k - 1] : (bg[k] ? j : fi[k]);
            }
            if (bg[0]) { fv[0] = val; fi[0] = j; }
        }
    }

    // ---- 4-way sorted-list tournament merge across the i-group (lanes l^16, l^32) ----
    // j-coverage disjoint across group lanes => winner pops exactly one head
    double w9v[KD]; int w9j[KD];
#pragma unroll
    for (int rd = 0; rd < KD; ++rd) {
        double hv = fv[0]; int hj = fi[0];
        {
            const double ov = __shfl_xor(hv, 16); const int oj = __shfl_xor(hj, 16);
            const bool tk = (ov > hv) || (ov == hv && oj < hj);
            hv = tk ? ov : hv; hj = tk ? oj : hj;
        }
        {
            const double ov = __shfl_xor(hv, 32); const int oj = __shfl_xor(hj, 32);
            const bool tk = (ov > hv) || (ov == hv && oj < hj);
            hv = tk ? ov : hv; hj = tk ? oj : hj;
        }
        w9v[rd] = hv; w9j[rd] = hj;
        const bool win = (fi[0] == hj);   // head sentinels impossible within 9 rounds
#pragma unroll
        for (int k = 0; k < KD - 1; ++k) {
            fv[k] = win ? fv[k + 1] : fv[k];
            fi[k] = win ? fi[k + 1] : fi[k];
        }
        if (win) fv[KD - 1] = -1.0e300;
    }

    // ---- outputs: all 4 group lanes hold identical winners; split the stores ----
    double wsum = 0.0;
#pragma unroll
    for (int k = 0; k < KD; ++k) wsum += w9v[k];
    const double winv = 1.0 / (wsum + 1e-8);

    const size_t base = ((size_t)f * HWD + i) * KD;
    const int sy = i / WD, sx = i - sy * WD;
    if (gr == 0) {
#pragma unroll
        for (int k = 0; k < KD; ++k) out[base + k] = (float)(w9v[k] * winv);
    } else if (gr == 1) {
#pragma unroll
        for (int k = 0; k < KD; ++k) out[OUTK + base + k] = (float)w9j[k];
    } else if (gr == 2) {
#pragma unroll
        for (int k = 0; k < KD; ++k) {
            const int j = w9j[k];
            out[2 * OUTK + (base + k) * 2 + 0] = (float)(j / WD - sy);
        }
    } else {
#pragma unroll
        for (int k = 0; k < KD; ++k) {
            const int j = w9j[k];
            out[2 * OUTK + (base + k) * 2 + 1] = (float)(j - (j / WD) * WD - sx);
        }
    }
}

extern "C" void kernel_launch(void* const* d_in, const int* in_sizes, int n_in,
                              void* d_out, int out_size, void* d_ws, size_t ws_size,
                              hipStream_t stream)
{
    const float* x = (const float*)d_in[0];
    uint*   fnw  = (uint*)((char*)d_ws + FNW_OFF);
    float*  traw = (float*)((char*)d_ws + TRAW_OFF);
    double* rnd  = (double*)((char*)d_ws + RND_OFF);
    float*  out  = (float*)d_out;

    prep_kernel<<<dim3((TD * BD * HWD * 4) / 256), 256, 0, stream>>>(x, fnw, traw, rnd);
    topk_kernel<<<dim3(NPAIR * 50), 256, 0, stream>>>(fnw, traw, rnd, out);
}